// Round 7
// baseline (105567.273 us; speedup 1.0000x reference)
//
#include <hip/hip_runtime.h>
#include <hip/hip_cooperative_groups.h>
#include <math.h>

namespace cg = cooperative_groups;
#define TMAX 200

__device__ __forceinline__ float sig_(float x){ return 1.0f/(1.0f+expf(-x)); }

// ws (k-major): xT[256][512] ; hT[1024][512] ; haT[2048][512]  (6.8 MB)
// Persistent cooperative kernel, grid-size-agnostic (units strided by gridDim.x).
// XCD-locality mapping: weight-group index in LOW 3 bits of unit id, so each of
// the 8 XCDs (block -> XCD = bid%8) touches only 1/8 of the weights -> L2-resident.
// Units: A = 512 (jg = u&63, bg = u>>6), B = 512 (ng = u&63, bg = u>>6),
//        C = 128 (cg = u&15 -> 16 cols, bg = u>>4).

__global__ __launch_bounds__(256, 2)
void kfused(const int* __restrict__ lengths,
            const float* __restrict__ eps,
            const float* __restrict__ W_ih, const float* __restrict__ b_ih,
            const float* __restrict__ b_hh,
            const float* __restrict__ W1a, const float* __restrict__ b1a,
            const float* __restrict__ W1b, const float* __restrict__ b1b,
            const float* __restrict__ W2a, const float* __restrict__ b2a,
            const float* __restrict__ W2b, const float* __restrict__ b2b,
            float* __restrict__ out_p1, float* __restrict__ out_p2, float* __restrict__ out_h,
            float* __restrict__ xT, float* __restrict__ hT, float* __restrict__ haT)
{
    __shared__ float stage[4096];
    __shared__ float aux[4096];
    __shared__ int sbs[TMAX], soff[TMAX];

    const int tid = threadIdx.x;
    const int bid = blockIdx.x;
    const int grd = gridDim.x;
    const int wv  = __builtin_amdgcn_readfirstlane(tid >> 6);   // 0..3
    const int l   = tid & 63;

    if (tid < TMAX) {
        int c = 0;
        for (int b = 0; b < 512; ++b) c += (lengths[b] > tid) ? 1 : 0;
        sbs[tid] = c;
    }
    __syncthreads();
    if (tid == 0) { int a = 0; for (int i = 0; i < TMAX; ++i) { soff[i] = a; a += sbs[i]; } }
    __syncthreads();

    cg::grid_group grid = cg::this_grid();

    for (int t = 0; t < TMAX; ++t) {
        const int bsz = sbs[t], ofs = soff[t];

        // ================= phase A: gi = x@W_ih^T -> GRU -> h =================
        for (int u = bid; u < 512; u += grd) {
            const int jg = u & 63, bg = u >> 6;       // weight group in low bits (XCD slice)
            const int bb = bg * 64, j0 = jg * 16;
            float accR[4] = {0.f,0.f,0.f,0.f};
            float accZ[4] = {0.f,0.f,0.f,0.f};
            float accN[4] = {0.f,0.f,0.f,0.f};
            if (t > 0) {
                float4 pf[4];
                #pragma unroll
                for (int i = 0; i < 4; ++i) {
                    const int idx = tid + i * 256;
                    pf[i] = *(const float4*)&xT[(size_t)(idx >> 4) * 512 + bb + (idx & 15) * 4];
                }
                #pragma unroll
                for (int i = 0; i < 4; ++i) {
                    const int idx = tid + i * 256;
                    *(float4*)&stage[(idx >> 4) * 64 + (idx & 15) * 4] = pf[i];
                }
                __syncthreads();
                for (int ch = 0; ch < 4; ++ch) {
                    const int k0 = ch * 64;
                    if (ch < 3) {
                        #pragma unroll
                        for (int i = 0; i < 4; ++i) {
                            const int idx = tid + i * 256;
                            pf[i] = *(const float4*)&xT[(size_t)(k0 + 64 + (idx >> 4)) * 512 + bb + (idx & 15) * 4];
                        }
                    }
                    #pragma unroll 4
                    for (int k4 = 0; k4 < 16; ++k4) {
                        const int kk = k4 * 4;
                        const float x0 = stage[(kk+0)*64 + l];
                        const float x1 = stage[(kk+1)*64 + l];
                        const float x2 = stage[(kk+2)*64 + l];
                        const float x3 = stage[(kk+3)*64 + l];
                        #pragma unroll
                        for (int q = 0; q < 4; ++q) {
                            const int jr = j0 + wv * 4 + q;
                            const float4 wr = *(const float4*)&W_ih[(size_t)jr * 256 + k0 + kk];
                            const float4 wz = *(const float4*)&W_ih[(size_t)(1024 + jr) * 256 + k0 + kk];
                            const float4 wn = *(const float4*)&W_ih[(size_t)(2048 + jr) * 256 + k0 + kk];
                            accR[q] = fmaf(x0,wr.x,fmaf(x1,wr.y,fmaf(x2,wr.z,fmaf(x3,wr.w,accR[q]))));
                            accZ[q] = fmaf(x0,wz.x,fmaf(x1,wz.y,fmaf(x2,wz.z,fmaf(x3,wz.w,accZ[q]))));
                            accN[q] = fmaf(x0,wn.x,fmaf(x1,wn.y,fmaf(x2,wn.z,fmaf(x3,wn.w,accN[q]))));
                        }
                    }
                    __syncthreads();
                    if (ch < 3) {
                        #pragma unroll
                        for (int i = 0; i < 4; ++i) {
                            const int idx = tid + i * 256;
                            *(float4*)&stage[(idx >> 4) * 64 + (idx & 15) * 4] = pf[i];
                        }
                        __syncthreads();
                    }
                }
            }
            #pragma unroll
            for (int q = 0; q < 4; ++q) {
                const int jr = j0 + wv * 4 + q;
                const float r = sig_(accR[q] + b_ih[jr] + b_hh[jr]);
                const float z = sig_(accZ[q] + b_ih[1024 + jr] + b_hh[1024 + jr]);
                const float n = tanhf(accN[q] + b_ih[2048 + jr] + r * b_hh[2048 + jr]);
                const float h = (1.f - z) * n;
                hT[(size_t)jr * 512 + bb + l] = h;
                aux[(wv * 4 + q) * 64 + l] = h;
            }
            __syncthreads();
            {
                const int b = tid >> 2, jj = (tid & 3) * 4;
                const int bglob = bb + b;
                if (bglob < bsz) {
                    float4 v = { aux[(jj+0)*64 + b], aux[(jj+1)*64 + b],
                                 aux[(jj+2)*64 + b], aux[(jj+3)*64 + b] };
                    *(float4*)&out_h[(size_t)(ofs + bglob) * 1024 + j0 + jj] = v;
                }
            }
            __syncthreads();
        }
        grid.sync();

        // ================= phase B: ha = tanh(h@Wa^T + ba) =================
        for (int u = bid; u < 512; u += grd) {
            const int ng = u & 63, bg = u >> 6;       // weight group in low bits
            const int bb = bg * 64, n0 = ng * 32;
            const int fam = (n0 >= 1024) ? 1 : 0;
            const float* __restrict__ Wa = fam ? W2a : W1a;
            const float* __restrict__ ba = fam ? b2a : b1a;
            const int nr0 = n0 - fam * 1024 + wv * 8;
            float acc[8] = {0.f,0.f,0.f,0.f,0.f,0.f,0.f,0.f};
            float4 pf[4];
            #pragma unroll
            for (int i = 0; i < 4; ++i) {
                const int idx = tid + i * 256;
                pf[i] = *(const float4*)&hT[(size_t)(idx >> 4) * 512 + bb + (idx & 15) * 4];
            }
            #pragma unroll
            for (int i = 0; i < 4; ++i) {
                const int idx = tid + i * 256;
                *(float4*)&stage[(idx >> 4) * 64 + (idx & 15) * 4] = pf[i];
            }
            __syncthreads();
            for (int ch = 0; ch < 16; ++ch) {
                const int k0 = ch * 64;
                if (ch < 15) {
                    #pragma unroll
                    for (int i = 0; i < 4; ++i) {
                        const int idx = tid + i * 256;
                        pf[i] = *(const float4*)&hT[(size_t)(k0 + 64 + (idx >> 4)) * 512 + bb + (idx & 15) * 4];
                    }
                }
                #pragma unroll 4
                for (int k4 = 0; k4 < 16; ++k4) {
                    const int kk = k4 * 4;
                    const float x0 = stage[(kk+0)*64 + l];
                    const float x1 = stage[(kk+1)*64 + l];
                    const float x2 = stage[(kk+2)*64 + l];
                    const float x3 = stage[(kk+3)*64 + l];
                    #pragma unroll
                    for (int c = 0; c < 8; ++c) {
                        const float4 w = *(const float4*)&Wa[(size_t)(nr0 + c) * 1024 + k0 + kk];
                        acc[c] = fmaf(x0,w.x,fmaf(x1,w.y,fmaf(x2,w.z,fmaf(x3,w.w,acc[c]))));
                    }
                }
                __syncthreads();
                if (ch < 15) {
                    #pragma unroll
                    for (int i = 0; i < 4; ++i) {
                        const int idx = tid + i * 256;
                        *(float4*)&stage[(idx >> 4) * 64 + (idx & 15) * 4] = pf[i];
                    }
                    __syncthreads();
                }
            }
            #pragma unroll
            for (int c = 0; c < 8; ++c)
                haT[(size_t)(n0 + wv * 8 + c) * 512 + bb + l] = tanhf(acc[c] + ba[nr0 + c]);
            __syncthreads();
        }
        grid.sync();

        // ====== phase C: p = ha@Wb^T + bb (16 cols/unit); scatter p; x_{t+1} fuse ======
        for (int u = bid; u < 128; u += grd) {
            const int cgi = u & 15, bg = u >> 4;      // weight group in low bits
            const int bb = bg * 64, c0 = cgi * 16;
            const int famC = wv >> 1, khC = wv & 1;
            const float* __restrict__ Wb = famC ? W2b : W1b;
            float acc[16];
            #pragma unroll
            for (int c = 0; c < 16; ++c) acc[c] = 0.f;
            float4 pf[4];
            #pragma unroll
            for (int i = 0; i < 4; ++i) {
                const int idx = tid + i * 256;
                const int w = idx >> 8, rem = idx & 255;
                const int rg = (w >> 1) * 1024 + (w & 1) * 512 + (rem >> 4);
                pf[i] = *(const float4*)&haT[(size_t)rg * 512 + bb + (rem & 15) * 4];
            }
            #pragma unroll
            for (int i = 0; i < 4; ++i) {
                const int idx = tid + i * 256;
                const int w = idx >> 8, rem = idx & 255;
                *(float4*)&stage[w * 1024 + (rem >> 4) * 64 + (rem & 15) * 4] = pf[i];
            }
            __syncthreads();
            for (int ch = 0; ch < 32; ++ch) {
                if (ch < 31) {
                    #pragma unroll
                    for (int i = 0; i < 4; ++i) {
                        const int idx = tid + i * 256;
                        const int w = idx >> 8, rem = idx & 255;
                        const int rg = (w >> 1) * 1024 + (w & 1) * 512 + (ch + 1) * 16 + (rem >> 4);
                        pf[i] = *(const float4*)&haT[(size_t)rg * 512 + bb + (rem & 15) * 4];
                    }
                }
                const int kb = khC * 512 + ch * 16;
                #pragma unroll
                for (int k4 = 0; k4 < 4; ++k4) {
                    const int kk = k4 * 4;
                    const float v0 = stage[wv * 1024 + (kk+0)*64 + l];
                    const float v1 = stage[wv * 1024 + (kk+1)*64 + l];
                    const float v2 = stage[wv * 1024 + (kk+2)*64 + l];
                    const float v3 = stage[wv * 1024 + (kk+3)*64 + l];
                    #pragma unroll
                    for (int c = 0; c < 16; ++c) {
                        const float4 w4 = *(const float4*)&Wb[(size_t)(c0 + c) * 1024 + kb + kk];
                        acc[c] = fmaf(v0,w4.x,fmaf(v1,w4.y,fmaf(v2,w4.z,fmaf(v3,w4.w,acc[c]))));
                    }
                }
                __syncthreads();
                if (ch < 31) {
                    #pragma unroll
                    for (int i = 0; i < 4; ++i) {
                        const int idx = tid + i * 256;
                        const int w = idx >> 8, rem = idx & 255;
                        *(float4*)&stage[w * 1024 + (rem >> 4) * 64 + (rem & 15) * 4] = pf[i];
                    }
                    __syncthreads();
                }
            }
            // deterministic cross-wave reduce: wv = fam*2 + khalf
            #pragma unroll
            for (int c = 0; c < 16; ++c) aux[wv * 1024 + c * 64 + l] = acc[c];
            __syncthreads();
            float p1s[4], p2s[4];
            #pragma unroll
            for (int p = 0; p < 4; ++p) {
                const int linear = p * 256 + tid;         // (c,b): c = linear>>6, b = linear&63
                const int c = linear >> 6, b = linear & 63;
                p1s[p] = aux[0*1024 + c*64 + b] + aux[1*1024 + c*64 + b] + b1b[c0 + c];
                p2s[p] = aux[2*1024 + c*64 + b] + aux[3*1024 + c*64 + b] + b2b[c0 + c];
            }
            __syncthreads();
            #pragma unroll
            for (int p = 0; p < 4; ++p) {                 // transpose to [b][c], stride 20 (8-bank spread, 4-aligned)
                const int linear = p * 256 + tid;
                const int c = linear >> 6, b = linear & 63;
                aux[b * 20 + c] = p1s[p];
                aux[1536 + b * 20 + c] = p2s[p];
            }
            __syncthreads();
            #pragma unroll
            for (int p = 0; p < 2; ++p) {                 // coalesced scatter of p rows
                const int idx = p * 256 + tid;            // (b, fam, c4)
                const int b = idx >> 3, q = idx & 7;
                const int fam2 = q >> 2, c4 = (q & 3) * 4;
                const int bglob = bb + b;
                if (bglob < bsz) {
                    const float4 v = *(const float4*)&aux[fam2 * 1536 + b * 20 + c4];
                    float* __restrict__ dst = fam2 ? out_p2 : out_p1;
                    *(float4*)&dst[(size_t)(ofs + bglob) * 256 + c0 + c4] = v;
                }
            }
            {   // x_{t+1} = p1 + exp(0.5 p2) * eps[t]
                const int b = tid >> 2, c4 = (tid & 3) * 4;
                const int bglob = bb + b;
                const float4 p1v = *(const float4*)&aux[b * 20 + c4];
                const float4 p2v = *(const float4*)&aux[1536 + b * 20 + c4];
                const float4 e = *(const float4*)&eps[(size_t)t * 131072 + (size_t)bglob * 256 + c0 + c4];
                xT[(size_t)(c0 + c4 + 0) * 512 + bglob] = fmaf(expf(0.5f * p2v.x), e.x, p1v.x);
                xT[(size_t)(c0 + c4 + 1) * 512 + bglob] = fmaf(expf(0.5f * p2v.y), e.y, p1v.y);
                xT[(size_t)(c0 + c4 + 2) * 512 + bglob] = fmaf(expf(0.5f * p2v.z), e.z, p1v.z);
                xT[(size_t)(c0 + c4 + 3) * 512 + bglob] = fmaf(expf(0.5f * p2v.w), e.w, p1v.w);
            }
            __syncthreads();
        }
        grid.sync();
    }
}

extern "C" void kernel_launch(void* const* d_in, const int* in_sizes, int n_in,
                              void* d_out, int out_size, void* d_ws, size_t ws_size,
                              hipStream_t stream)
{
    (void)in_sizes; (void)n_in; (void)ws_size;
    const int*   lengths = (const int*)  d_in[1];
    const float* eps     = (const float*)d_in[2];
    const float* W_ih    = (const float*)d_in[5];
    const float* b_ih    = (const float*)d_in[6];
    const float* b_hh    = (const float*)d_in[8];
    const float* W1a     = (const float*)d_in[9];
    const float* b1a     = (const float*)d_in[10];
    const float* W1b     = (const float*)d_in[11];
    const float* b1b     = (const float*)d_in[12];
    const float* W2a     = (const float*)d_in[13];
    const float* b2a     = (const float*)d_in[14];
    const float* W2b     = (const float*)d_in[15];
    const float* b2b     = (const float*)d_in[16];

    float* out = (float*)d_out;
    const size_t N = (size_t)out_size / 1536;
    float* out_p1 = out;
    float* out_p2 = out + N * 256;
    float* out_h  = out + N * 512;

    float* xT  = (float*)d_ws;          // [256][512]
    float* hT  = xT + 131072;           // [1024][512]
    float* haT = hT + 524288;           // [2048][512]   total 6.8 MB

    // Size the grid to what the RUNTIME says can be co-resident (launch cannot fail).
    int dev = 0;
    (void)hipGetDevice(&dev);
    int ncu = 0;
    if (hipDeviceGetAttribute(&ncu, hipDeviceAttributeMultiprocessorCount, dev) != hipSuccess || ncu <= 0)
        ncu = 256;
    int maxB = 0;
    if (hipOccupancyMaxActiveBlocksPerMultiprocessor(&maxB, (const void*)kfused, 256, 0) != hipSuccess || maxB <= 0)
        maxB = 1;
    long cap = (long)maxB * (long)ncu;
    int grd = (cap < 512) ? (int)cap : 512;
    if (grd < 1) grd = 1;

    void* args[] = {
        (void*)&lengths, (void*)&eps, (void*)&W_ih, (void*)&b_ih, (void*)&b_hh,
        (void*)&W1a, (void*)&b1a, (void*)&W1b, (void*)&b1b,
        (void*)&W2a, (void*)&b2a, (void*)&W2b, (void*)&b2b,
        (void*)&out_p1, (void*)&out_p2, (void*)&out_h,
        (void*)&xT, (void*)&hT, (void*)&haT
    };
    hipLaunchCooperativeKernel((void*)kfused, dim3(grd), dim3(256), args, 0, stream);
}

// Round 8
// 77968.530 us; speedup vs baseline: 1.3540x; 1.3540x over previous
//
#include <hip/hip_runtime.h>
#include <hip/hip_cooperative_groups.h>
#include <math.h>

namespace cg = cooperative_groups;
#define TMAX 200

__device__ __forceinline__ float sig_(float x){ return 1.0f/(1.0f+expf(-x)); }

// ws (all k-major): xT[256][512]; hT[1024][512]; haT[2048][512]; pT1[256][512]; pT2[256][512]
// Persistent cooperative kernel. R3-proven structure: NO syncthreads in GEMM inner
// loops, activations streamed from L2 (float2/lane), weights wave-uniform float4.
// 2x finer units (1024/phase, 128 batches) + __launch_bounds__(256,4) + ~18KB LDS
// -> occupancy-sized grid up to 1024 blocks = 16 waves/CU (2x R3's TLP).
// XCD locality (bid%8): A/B weight-group in low bits (W/8 + full acts < 3MB/XCD);
// C: (cg&1, bg) low bits (Wb/2=1MB + haT bg-slice 1MB).

__global__ __launch_bounds__(256, 4)
void kfused(const int* __restrict__ lengths,
            const float* __restrict__ eps,
            const float* __restrict__ W_ih, const float* __restrict__ b_ih,
            const float* __restrict__ b_hh,
            const float* __restrict__ W1a, const float* __restrict__ b1a,
            const float* __restrict__ W1b, const float* __restrict__ b1b,
            const float* __restrict__ W2a, const float* __restrict__ b2a,
            const float* __restrict__ W2b, const float* __restrict__ b2b,
            float* __restrict__ out_p1, float* __restrict__ out_p2, float* __restrict__ out_h,
            float* __restrict__ xT, float* __restrict__ hT, float* __restrict__ haT,
            float* __restrict__ pT1, float* __restrict__ pT2)
{
    __shared__ float red[4096];          // 16 KB, reused per phase
    __shared__ int sbs[TMAX], soff[TMAX];

    const int tid = threadIdx.x;
    const int bid = blockIdx.x;
    const int grd = gridDim.x;
    const int wv  = __builtin_amdgcn_readfirstlane(tid >> 6);   // 0..3
    const int l   = tid & 63;

    if (tid < TMAX) {
        int c = 0;
        for (int b = 0; b < 512; ++b) c += (lengths[b] > tid) ? 1 : 0;
        sbs[tid] = c;
    }
    __syncthreads();
    if (tid == 0) { int a = 0; for (int i = 0; i < TMAX; ++i) { soff[i] = a; a += sbs[i]; } }
    __syncthreads();

    cg::grid_group grid = cg::this_grid();

    for (int t = 0; t < TMAX; ++t) {
        const int bsz = sbs[t], ofs = soff[t];

        // ========== phase A: gi = x@W_ih^T -> GRU -> h  (+ scatter p_{t-1}) ==========
        for (int u = bid; u < 1056; u += grd) {
            if (u < 1024) {
                const int jg = u & 255, bg = u >> 8;     // weight grp low bits (XCD slice)
                const int bb = bg * 128;
                const int j = jg * 4 + wv;
                float aR0=0.f,aR1=0.f,aZ0=0.f,aZ1=0.f,aN0=0.f,aN1=0.f;
                if (t > 0) {
                    const float* __restrict__ xp = xT + bb + l * 2;
                    for (int k = 0; k < 256; k += 4) {
                        const float2 x0 = *(const float2*)(xp + (size_t)(k+0)*512);
                        const float2 x1 = *(const float2*)(xp + (size_t)(k+1)*512);
                        const float2 x2 = *(const float2*)(xp + (size_t)(k+2)*512);
                        const float2 x3 = *(const float2*)(xp + (size_t)(k+3)*512);
                        const float4 wr = *(const float4*)&W_ih[(size_t)j*256 + k];
                        const float4 wz = *(const float4*)&W_ih[(size_t)(1024+j)*256 + k];
                        const float4 wn = *(const float4*)&W_ih[(size_t)(2048+j)*256 + k];
                        aR0 = fmaf(x3.x,wr.w,fmaf(x2.x,wr.z,fmaf(x1.x,wr.y,fmaf(x0.x,wr.x,aR0))));
                        aR1 = fmaf(x3.y,wr.w,fmaf(x2.y,wr.z,fmaf(x1.y,wr.y,fmaf(x0.y,wr.x,aR1))));
                        aZ0 = fmaf(x3.x,wz.w,fmaf(x2.x,wz.z,fmaf(x1.x,wz.y,fmaf(x0.x,wz.x,aZ0))));
                        aZ1 = fmaf(x3.y,wz.w,fmaf(x2.y,wz.z,fmaf(x1.y,wz.y,fmaf(x0.y,wz.x,aZ1))));
                        aN0 = fmaf(x3.x,wn.w,fmaf(x2.x,wn.z,fmaf(x1.x,wn.y,fmaf(x0.x,wn.x,aN0))));
                        aN1 = fmaf(x3.y,wn.w,fmaf(x2.y,wn.z,fmaf(x1.y,wn.y,fmaf(x0.y,wn.x,aN1))));
                    }
                }
                const float br = b_ih[j] + b_hh[j];
                const float bz = b_ih[1024+j] + b_hh[1024+j];
                const float bn = b_ih[2048+j];
                const float gn = b_hh[2048+j];
                float2 h;
                {
                    const float r0 = sig_(aR0 + br), z0 = sig_(aZ0 + bz);
                    const float r1 = sig_(aR1 + br), z1 = sig_(aZ1 + bz);
                    h.x = (1.f - z0) * tanhf(aN0 + bn + r0 * gn);
                    h.y = (1.f - z1) * tanhf(aN1 + bn + r1 * gn);
                }
                *(float2*)&hT[(size_t)j * 512 + bb + l * 2] = h;
                red[wv * 128 + l * 2]     = h.x;
                red[wv * 128 + l * 2 + 1] = h.y;
                __syncthreads();
                if (tid < 128) {
                    const int b = tid, bglob = bb + b;
                    if (bglob < bsz) {
                        float4 v = { red[b], red[128 + b], red[256 + b], red[384 + b] };
                        *(float4*)&out_h[(size_t)(ofs + bglob) * 1024 + jg * 4] = v;
                    }
                }
                __syncthreads();
            } else if (t > 0) {
                // coalesced scatter of p_{t-1}: 32 sub-units, 16 packed rows each
                const int s = u - 1024;
                const int bbase = s * 16;
                const int bsp = sbs[t-1], ofp = soff[t-1];
                for (int fam = 0; fam < 2; ++fam) {
                    const float* __restrict__ src = fam ? pT2 : pT1;
                    #pragma unroll
                    for (int i = 0; i < 16; ++i) {
                        const int idx = tid + i * 256, c = idx >> 4, f = idx & 15;
                        red[c * 16 + f] = src[(size_t)c * 512 + bbase + f];
                    }
                    __syncthreads();
                    {
                        const int b = tid >> 4, ct = tid & 15;
                        const int bglob = bbase + b;
                        if (bglob < bsp) {
                            float* __restrict__ dst = fam ? out_p2 : out_p1;
                            #pragma unroll
                            for (int q = 0; q < 4; ++q) {
                                const int c = ct * 16 + q * 4;
                                float4 v = { red[(c+0)*16 + b], red[(c+1)*16 + b],
                                             red[(c+2)*16 + b], red[(c+3)*16 + b] };
                                *(float4*)&dst[(size_t)(ofp + bglob) * 256 + c] = v;
                            }
                        }
                    }
                    __syncthreads();
                }
            }
        }
        grid.sync();

        // ========== phase B: ha = tanh(h @ Wa^T + ba), K-split 4 waves ==========
        for (int u = bid; u < 1024; u += grd) {
            const int ng = u & 255, bg = u >> 8;         // weight grp low bits
            const int bb = bg * 128, n0 = ng * 8;
            const int fam = (n0 >= 1024) ? 1 : 0;
            const float* __restrict__ Wa = fam ? W2a : W1a;
            const float* __restrict__ ba = fam ? b2a : b1a;
            const int nr0 = n0 - fam * 1024;
            const int kb = wv * 256;
            float2 acc[8];
            #pragma unroll
            for (int c = 0; c < 8; ++c) acc[c] = make_float2(0.f, 0.f);
            const float* __restrict__ hp = hT + (size_t)kb * 512 + bb + l * 2;
            for (int k4 = 0; k4 < 64; ++k4) {
                const int k = k4 * 4;
                const float2 h0 = *(const float2*)(hp + (size_t)(k+0)*512);
                const float2 h1 = *(const float2*)(hp + (size_t)(k+1)*512);
                const float2 h2 = *(const float2*)(hp + (size_t)(k+2)*512);
                const float2 h3 = *(const float2*)(hp + (size_t)(k+3)*512);
                #pragma unroll
                for (int c = 0; c < 8; ++c) {
                    const float4 w = *(const float4*)&Wa[(size_t)(nr0 + c) * 1024 + kb + k];
                    acc[c].x = fmaf(h3.x,w.w,fmaf(h2.x,w.z,fmaf(h1.x,w.y,fmaf(h0.x,w.x,acc[c].x))));
                    acc[c].y = fmaf(h3.y,w.w,fmaf(h2.y,w.z,fmaf(h1.y,w.y,fmaf(h0.y,w.x,acc[c].y))));
                }
            }
            #pragma unroll
            for (int c = 0; c < 8; ++c) {
                red[wv * 1024 + c * 128 + l * 2]     = acc[c].x;
                red[wv * 1024 + c * 128 + l * 2 + 1] = acc[c].y;
            }
            __syncthreads();
            {
                const int c = tid >> 5, b4 = (tid & 31) * 4;
                float4 s = *(const float4*)&red[c * 128 + b4];
                #pragma unroll
                for (int w = 1; w < 4; ++w) {
                    const float4 p = *(const float4*)&red[w * 1024 + c * 128 + b4];
                    s.x += p.x; s.y += p.y; s.z += p.z; s.w += p.w;
                }
                const float bias = ba[nr0 + c];
                s.x = tanhf(s.x + bias); s.y = tanhf(s.y + bias);
                s.z = tanhf(s.z + bias); s.w = tanhf(s.w + bias);
                *(float4*)&haT[(size_t)(n0 + c) * 512 + bb + b4] = s;
            }
            __syncthreads();
        }
        grid.sync();

        // ========== phase C: p = ha @ Wb^T + bb -> pT (coalesced) + x-fuse ==========
        for (int u = bid; u < 1024; u += grd) {
            const int cgi = u >> 2, bg = u & 3;          // low bits: (cg&1, bg) XCD slice
            const int bb = bg * 128, c = cgi;
            const int kb = wv * 256;
            float2 a1 = make_float2(0.f, 0.f), a2 = make_float2(0.f, 0.f);
            const float* __restrict__ hp1 = haT + (size_t)kb * 512 + bb + l * 2;
            const float* __restrict__ hp2 = haT + (size_t)(1024 + kb) * 512 + bb + l * 2;
            for (int k4 = 0; k4 < 64; ++k4) {
                const int k = k4 * 4;
                const float2 u0 = *(const float2*)(hp1 + (size_t)(k+0)*512);
                const float2 u1 = *(const float2*)(hp1 + (size_t)(k+1)*512);
                const float2 u2 = *(const float2*)(hp1 + (size_t)(k+2)*512);
                const float2 u3 = *(const float2*)(hp1 + (size_t)(k+3)*512);
                const float2 v0 = *(const float2*)(hp2 + (size_t)(k+0)*512);
                const float2 v1 = *(const float2*)(hp2 + (size_t)(k+1)*512);
                const float2 v2 = *(const float2*)(hp2 + (size_t)(k+2)*512);
                const float2 v3 = *(const float2*)(hp2 + (size_t)(k+3)*512);
                const float4 w1 = *(const float4*)&W1b[(size_t)c * 1024 + kb + k];
                const float4 w2 = *(const float4*)&W2b[(size_t)c * 1024 + kb + k];
                a1.x = fmaf(u3.x,w1.w,fmaf(u2.x,w1.z,fmaf(u1.x,w1.y,fmaf(u0.x,w1.x,a1.x))));
                a1.y = fmaf(u3.y,w1.w,fmaf(u2.y,w1.z,fmaf(u1.y,w1.y,fmaf(u0.y,w1.x,a1.y))));
                a2.x = fmaf(v3.x,w2.w,fmaf(v2.x,w2.z,fmaf(v1.x,w2.y,fmaf(v0.x,w2.x,a2.x))));
                a2.y = fmaf(v3.y,w2.w,fmaf(v2.y,w2.z,fmaf(v1.y,w2.y,fmaf(v0.y,w2.x,a2.y))));
            }
            red[(wv*2+0)*128 + l*2]     = a1.x;
            red[(wv*2+0)*128 + l*2 + 1] = a1.y;
            red[(wv*2+1)*128 + l*2]     = a2.x;
            red[(wv*2+1)*128 + l*2 + 1] = a2.y;
            __syncthreads();
            {
                const int fm = tid >> 7, b = tid & 127;
                float p = red[fm*128 + b] + red[(2+fm)*128 + b]
                        + red[(4+fm)*128 + b] + red[(6+fm)*128 + b];
                p += fm ? b2b[c] : b1b[c];
                (fm ? pT2 : pT1)[(size_t)c * 512 + bb + b] = p;   // coalesced
                red[1024 + fm * 128 + b] = p;
            }
            __syncthreads();
            if (tid < 128) {
                const int b = tid, bglob = bb + b;
                const float p1 = red[1024 + b], p2 = red[1024 + 128 + b];
                const float e = eps[(size_t)t * 131072 + (size_t)bglob * 256 + c];
                xT[(size_t)c * 512 + bglob] = fmaf(expf(0.5f * p2), e, p1);  // coalesced
            }
            __syncthreads();
        }
        grid.sync();
    }

    // ---- final scatter of p_199 ----
    {
        const int bsp = sbs[TMAX-1], ofp = soff[TMAX-1];
        for (int u = bid; u < 32; u += grd) {
            const int bbase = u * 16;
            for (int fam = 0; fam < 2; ++fam) {
                const float* __restrict__ src = fam ? pT2 : pT1;
                #pragma unroll
                for (int i = 0; i < 16; ++i) {
                    const int idx = tid + i * 256, c = idx >> 4, f = idx & 15;
                    red[c * 16 + f] = src[(size_t)c * 512 + bbase + f];
                }
                __syncthreads();
                {
                    const int b = tid >> 4, ct = tid & 15;
                    const int bglob = bbase + b;
                    if (bglob < bsp) {
                        float* __restrict__ dst = fam ? out_p2 : out_p1;
                        #pragma unroll
                        for (int q = 0; q < 4; ++q) {
                            const int c = ct * 16 + q * 4;
                            float4 v = { red[(c+0)*16 + b], red[(c+1)*16 + b],
                                         red[(c+2)*16 + b], red[(c+3)*16 + b] };
                            *(float4*)&dst[(size_t)(ofp + bglob) * 256 + c] = v;
                        }
                    }
                }
                __syncthreads();
            }
        }
    }
}

extern "C" void kernel_launch(void* const* d_in, const int* in_sizes, int n_in,
                              void* d_out, int out_size, void* d_ws, size_t ws_size,
                              hipStream_t stream)
{
    (void)in_sizes; (void)n_in; (void)ws_size;
    const int*   lengths = (const int*)  d_in[1];
    const float* eps     = (const float*)d_in[2];
    const float* W_ih    = (const float*)d_in[5];
    const float* b_ih    = (const float*)d_in[6];
    const float* b_hh    = (const float*)d_in[8];
    const float* W1a     = (const float*)d_in[9];
    const float* b1a     = (const float*)d_in[10];
    const float* W1b     = (const float*)d_in[11];
    const float* b1b     = (const float*)d_in[12];
    const float* W2a     = (const float*)d_in[13];
    const float* b2a     = (const float*)d_in[14];
    const float* W2b     = (const float*)d_in[15];
    const float* b2b     = (const float*)d_in[16];

    float* out = (float*)d_out;
    const size_t N = (size_t)out_size / 1536;
    float* out_p1 = out;
    float* out_p2 = out + N * 256;
    float* out_h  = out + N * 512;

    float* xT  = (float*)d_ws;           // [256][512]
    float* hT  = xT  + 131072;           // [1024][512]
    float* haT = hT  + 524288;           // [2048][512]
    float* pT1 = haT + 1048576;          // [256][512]
    float* pT2 = pT1 + 131072;           // [256][512]   total ~7.9 MB

    // Grid sized by the runtime's own co-residency answer (launch cannot fail).
    int dev = 0;
    (void)hipGetDevice(&dev);
    int ncu = 0;
    if (hipDeviceGetAttribute(&ncu, hipDeviceAttributeMultiprocessorCount, dev) != hipSuccess || ncu <= 0)
        ncu = 256;
    int maxB = 0;
    if (hipOccupancyMaxActiveBlocksPerMultiprocessor(&maxB, (const void*)kfused, 256, 0) != hipSuccess || maxB <= 0)
        maxB = 1;
    long cap = (long)maxB * (long)ncu;
    int grd = (cap < 1024) ? (int)cap : 1024;
    if (grd < 1) grd = 1;

    void* args[] = {
        (void*)&lengths, (void*)&eps, (void*)&W_ih, (void*)&b_ih, (void*)&b_hh,
        (void*)&W1a, (void*)&b1a, (void*)&W1b, (void*)&b1b,
        (void*)&W2a, (void*)&b2a, (void*)&W2b, (void*)&b2b,
        (void*)&out_p1, (void*)&out_p2, (void*)&out_h,
        (void*)&xT, (void*)&hT, (void*)&haT, (void*)&pT1, (void*)&pT2
    };
    hipLaunchCooperativeKernel((void*)kfused, dim3(grd), dim3(256), args, 0, stream);
}